// Round 3
// baseline (1508.506 us; speedup 1.0000x reference)
//
#include <hip/hip_runtime.h>
#include <hip/hip_bf16.h>
#include <stdint.h>

// Problem constants (from reference)
constexpr int B_    = 4;
constexpr int TG_   = 32768;
constexpr int D_    = 128;
constexpr int KOUT_ = 2048;
#define BIGF 1e9f

// Monotonic float->uint map (ascending)
__device__ __forceinline__ uint32_t f2u_asc(float f) {
  uint32_t b = __float_as_uint(f);
  return (b & 0x80000000u) ? ~b : (b | 0x80000000u);
}
__device__ __forceinline__ float u2f_asc(uint32_t u) {
  uint32_t b = (u & 0x80000000u) ? (u & 0x7FFFFFFFu) : ~u;
  return __uint_as_float(b);
}

// mask dtype sniff: int32-bool array has first 16 words all in {0,1};
// a uint8-bool array (90% ones) cannot (P ~ 1e-48).
__device__ __forceinline__ bool mask_is_i32(const void* mask_raw) {
  const uint32_t* mw = (const uint32_t*)mask_raw;
  bool i32 = true;
  #pragma unroll
  for (int j = 0; j < 16; ++j) i32 &= (mw[j] <= 1u);
  return i32;
}
__device__ __forceinline__ int read_mask(const void* mask_raw, int idx, bool i32) {
  return i32 ? ((const int*)mask_raw)[idx]
             : (int)((const unsigned char*)mask_raw)[idx];
}

// One wave (64 lanes) per grounding. Computes DistMult min-conjunction score,
// applies mask, emits 64-bit sort key = (~asc(score) << 32) | t.
__global__ __launch_bounds__(256) void score_kernel(
    const int* __restrict__ body, const void* __restrict__ mask,
    const float* __restrict__ ent, const float* __restrict__ rel,
    unsigned long long* __restrict__ keys) {
  int wid  = (blockIdx.x * 256 + threadIdx.x) >> 6;   // grounding id, 0..B*TG-1
  int lane = threadIdx.x & 63;
  if (wid >= B_ * TG_) return;
  bool mi32 = mask_is_i32(mask);
  const int* atom = body + (long)wid * 12;            // [M=4][3]
  float mins = BIGF;
  #pragma unroll
  for (int m = 0; m < 4; ++m) {
    int sid = atom[m * 3 + 0];                        // wave-uniform
    if (sid != 0) {                                   // uniform branch
      int rid = atom[m * 3 + 1];
      int oid = atom[m * 3 + 2];
      float2 s2 = *(const float2*)(ent + (long)sid * D_ + lane * 2);
      float2 r2 = *(const float2*)(rel + (long)rid * D_ + lane * 2);
      float2 o2 = *(const float2*)(ent + (long)oid * D_ + lane * 2);
      float p = s2.x * r2.x * o2.x + s2.y * r2.y * o2.y;
      #pragma unroll
      for (int off = 32; off > 0; off >>= 1) p += __shfl_xor(p, off, 64);
      mins = fminf(mins, p);
    }
  }
  float score = read_mask(mask, wid, mi32) ? mins : -BIGF;
  if (lane == 0) {
    uint32_t dk = ~f2u_asc(score);                    // ascending dk == descending score
    uint32_t t  = (uint32_t)(wid & (TG_ - 1));
    keys[wid] = ((unsigned long long)dk << 32) | t;   // ties -> lower t first
  }
}

// Full bitonic sort (ascending u64) of one row of 32768 keys per block.
__global__ __launch_bounds__(1024) void sort_kernel(unsigned long long* __restrict__ keys) {
  unsigned long long* a = keys + (long)blockIdx.x * TG_;
  const int n = TG_;
  for (int k = 2; k <= n; k <<= 1) {
    for (int j = k >> 1; j > 0; j >>= 1) {
      __syncthreads();
      for (int i = threadIdx.x; i < n; i += 1024) {
        int l = i ^ j;
        if (l > i) {
          unsigned long long ai = a[i], al = a[l];
          bool up = ((i & k) == 0);
          if ((ai > al) == up) { a[i] = al; a[l] = ai; }
        }
      }
    }
  }
}

// Gather selected groundings and emit all four outputs as FLOAT32
// (harness reads d_out as float32; comparison bf16-rounds both sides).
__global__ __launch_bounds__(256) void out_kernel(
    const unsigned long long* __restrict__ keys, const int* __restrict__ body,
    const void* __restrict__ mask, const int* __restrict__ rule,
    float* __restrict__ out) {
  int idx = blockIdx.x * 256 + threadIdx.x;           // 0..B*KOUT-1
  if (idx >= B_ * KOUT_) return;
  bool mi32 = mask_is_i32(mask);
  int b = idx / KOUT_, k = idx % KOUT_;
  unsigned long long key = keys[(long)b * TG_ + k];   // k-th largest score
  int t = (int)(key & 0xFFFFFFFFu);
  float score = u2f_asc(~(uint32_t)(key >> 32));
  int g = b * TG_ + t;
  const int* atom = body + (long)g * 12;
  float* ob = out + (long)idx * 12;                   // body_sel section [0, 98304)
  #pragma unroll
  for (int c = 0; c < 12; ++c) ob[c] = (float)atom[c];
  const int base1 = B_ * KOUT_ * 12;                  // 98304: mask_sel
  out[base1 + idx]                  = read_mask(mask, g, mi32) ? 1.0f : 0.0f;
  out[base1 + B_ * KOUT_ + idx]     = (float)rule[g];     // rule_sel
  out[base1 + 2 * B_ * KOUT_ + idx] = score;              // top_scores
}

extern "C" void kernel_launch(void* const* d_in, const int* in_sizes, int n_in,
                              void* d_out, int out_size, void* d_ws, size_t ws_size,
                              hipStream_t stream) {
  const int*  body = (const int*)d_in[0];
  const void* mask = d_in[1];
  const int*  rule = (const int*)d_in[2];
  const float* ent = (const float*)d_in[3];
  const float* rel = (const float*)d_in[4];
  float* out = (float*)d_out;
  unsigned long long* keys = (unsigned long long*)d_ws;   // B*TG u64 = 1 MiB

  // 1) score: one wave per grounding; 4 waves per 256-thread block
  score_kernel<<<(B_ * TG_) / 4, 256, 0, stream>>>(body, mask, ent, rel, keys);
  // 2) per-row bitonic sort of the 64-bit keys
  sort_kernel<<<B_, 1024, 0, stream>>>(keys);
  // 3) gather + emit float32 outputs
  out_kernel<<<(B_ * KOUT_ + 255) / 256, 256, 0, stream>>>(keys, body, mask, rule, out);
}

// Round 4
// 189.255 us; speedup vs baseline: 7.9707x; 7.9707x over previous
//
#include <hip/hip_runtime.h>
#include <hip/hip_bf16.h>
#include <stdint.h>

// Problem constants (from reference)
constexpr int B_    = 4;
constexpr int TG_   = 32768;
constexpr int D_    = 128;
constexpr int KOUT_ = 2048;
constexpr int NB_   = 256;    // radix buckets (8 bits)
constexpr int CAP_  = 4096;   // candidate buffer (power of 2, >= KOUT + tie group)
#define BIGF 1e9f

// Monotonic float->uint map (ascending)
__device__ __forceinline__ uint32_t f2u_asc(float f) {
  uint32_t b = __float_as_uint(f);
  return (b & 0x80000000u) ? ~b : (b | 0x80000000u);
}
__device__ __forceinline__ float u2f_asc(uint32_t u) {
  uint32_t b = (u & 0x80000000u) ? (u & 0x7FFFFFFFu) : ~u;
  return __uint_as_float(b);
}

// mask dtype sniff: int32-bool array has first 16 words all in {0,1};
// a uint8-bool array (90% ones) cannot (P ~ 1e-48).
__device__ __forceinline__ bool mask_is_i32(const void* mask_raw) {
  const uint32_t* mw = (const uint32_t*)mask_raw;
  bool i32 = true;
  #pragma unroll
  for (int j = 0; j < 16; ++j) i32 &= (mw[j] <= 1u);
  return i32;
}
__device__ __forceinline__ int read_mask(const void* mask_raw, int idx, bool i32) {
  return i32 ? ((const int*)mask_raw)[idx]
             : (int)((const unsigned char*)mask_raw)[idx];
}

// One wave (64 lanes) per grounding. Computes DistMult min-conjunction score,
// applies mask, emits 64-bit sort key = (~asc(score) << 32) | t.
// Ascending key order == descending score, ties -> lower index (jax top_k).
__global__ __launch_bounds__(256) void score_kernel(
    const int* __restrict__ body, const void* __restrict__ mask,
    const float* __restrict__ ent, const float* __restrict__ rel,
    unsigned long long* __restrict__ keys) {
  int wid  = (blockIdx.x * 256 + threadIdx.x) >> 6;   // grounding id, 0..B*TG-1
  int lane = threadIdx.x & 63;
  if (wid >= B_ * TG_) return;
  bool mi32 = mask_is_i32(mask);
  const int* atom = body + (long)wid * 12;            // [M=4][3]
  float mins = BIGF;
  #pragma unroll
  for (int m = 0; m < 4; ++m) {
    int sid = atom[m * 3 + 0];                        // wave-uniform
    if (sid != 0) {                                   // uniform branch
      int rid = atom[m * 3 + 1];
      int oid = atom[m * 3 + 2];
      float2 s2 = *(const float2*)(ent + (long)sid * D_ + lane * 2);
      float2 r2 = *(const float2*)(rel + (long)rid * D_ + lane * 2);
      float2 o2 = *(const float2*)(ent + (long)oid * D_ + lane * 2);
      float p = s2.x * r2.x * o2.x + s2.y * r2.y * o2.y;
      #pragma unroll
      for (int off = 32; off > 0; off >>= 1) p += __shfl_xor(p, off, 64);
      mins = fminf(mins, p);
    }
  }
  float score = read_mask(mask, wid, mi32) ? mins : -BIGF;
  if (lane == 0) {
    uint32_t dk = ~f2u_asc(score);
    uint32_t t  = (uint32_t)(wid & (TG_ - 1));
    keys[wid] = ((unsigned long long)dk << 32) | t;
  }
}

// Per-row exact top-KOUT selection, replacing the full bitonic sort.
// 1) radix-select (4x8 bits over dk = key>>32) the dk of the KOUT-th
//    smallest key; 2) compact keys with dk <= dk_th into LDS; 3) bitonic
//    sort CAP_ (padded) in LDS; 4) write smallest KOUT back to row front.
__global__ __launch_bounds__(1024) void select_kernel(unsigned long long* __restrict__ keys) {
  unsigned long long* a = keys + (long)blockIdx.x * TG_;
  __shared__ uint32_t hist[4][NB_];     // privatized to cut LDS-atomic contention
  __shared__ uint32_t scan_[NB_];
  __shared__ unsigned long long cand[CAP_];
  __shared__ uint32_t s_cnt;
  __shared__ uint32_t s_prefix;
  __shared__ int s_k;
  int tid = threadIdx.x;
  int hcopy = (tid >> 8) & 3;

  if (tid == 0) s_cnt = 0;
  uint32_t prefix = 0;
  int k = KOUT_;                        // rank (1-based) among prefix-matching keys
  #pragma unroll
  for (int pass = 0; pass < 4; ++pass) {
    int shift = 24 - pass * 8;
    for (int i = tid; i < 4 * NB_; i += 1024) ((uint32_t*)hist)[i] = 0;
    __syncthreads();
    uint32_t pmask = (pass == 0) ? 0u : (0xFFFFFFFFu << (shift + 8));
    for (int i = tid; i < TG_; i += 1024) {
      uint32_t dk = (uint32_t)(a[i] >> 32);
      if ((dk & pmask) == prefix)
        atomicAdd(&hist[hcopy][(dk >> shift) & 0xFF], 1u);
    }
    __syncthreads();
    if (tid < NB_)
      scan_[tid] = hist[0][tid] + hist[1][tid] + hist[2][tid] + hist[3][tid];
    __syncthreads();
    // inclusive prefix sum (Hillis-Steele) over NB_ entries
    for (int off = 1; off < NB_; off <<= 1) {
      uint32_t v = 0;
      if (tid < NB_ && tid >= off) v = scan_[tid - off];
      __syncthreads();
      if (tid < NB_) scan_[tid] += v;
      __syncthreads();
    }
    if (tid < NB_) {
      uint32_t above = (tid == 0) ? 0u : scan_[tid - 1];
      if (scan_[tid] >= (uint32_t)k && above < (uint32_t)k) {  // unique d
        s_prefix = prefix | ((uint32_t)tid << shift);
        s_k = k - (int)above;
      }
    }
    __syncthreads();
    prefix = s_prefix;
    k = s_k;
    __syncthreads();
  }
  uint32_t dk_th = prefix;              // dk of the KOUT-th smallest key

  // Compact candidates: all keys at-or-below the threshold dk group.
  for (int i = tid; i < TG_; i += 1024) {
    unsigned long long key = a[i];
    if ((uint32_t)(key >> 32) <= dk_th) {
      uint32_t pos = atomicAdd(&s_cnt, 1u);
      if (pos < CAP_) cand[pos] = key;
    }
  }
  __syncthreads();
  uint32_t n_cand = s_cnt < (uint32_t)CAP_ ? s_cnt : (uint32_t)CAP_;
  for (int i = (int)n_cand + tid; i < CAP_; i += 1024) cand[i] = ~0ull;
  __syncthreads();
  // Bitonic sort CAP_ elements ascending in LDS.
  for (int kk = 2; kk <= CAP_; kk <<= 1) {
    for (int j = kk >> 1; j > 0; j >>= 1) {
      for (int i = tid; i < CAP_; i += 1024) {
        int l = i ^ j;
        if (l > i) {
          unsigned long long ai = cand[i], al = cand[l];
          bool up = ((i & kk) == 0);
          if ((ai > al) == up) { cand[i] = al; cand[l] = ai; }
        }
      }
      __syncthreads();
    }
  }
  for (int i = tid; i < KOUT_; i += 1024) a[i] = cand[i];
}

// Gather selected groundings and emit all four outputs as FLOAT32.
__global__ __launch_bounds__(256) void out_kernel(
    const unsigned long long* __restrict__ keys, const int* __restrict__ body,
    const void* __restrict__ mask, const int* __restrict__ rule,
    float* __restrict__ out) {
  int idx = blockIdx.x * 256 + threadIdx.x;           // 0..B*KOUT-1
  if (idx >= B_ * KOUT_) return;
  bool mi32 = mask_is_i32(mask);
  int b = idx / KOUT_, k = idx % KOUT_;
  unsigned long long key = keys[(long)b * TG_ + k];   // k-th largest score
  int t = (int)(key & 0xFFFFFFFFu);
  float score = u2f_asc(~(uint32_t)(key >> 32));
  int g = b * TG_ + t;
  const int* atom = body + (long)g * 12;
  float* ob = out + (long)idx * 12;                   // body_sel [0, 98304)
  #pragma unroll
  for (int c = 0; c < 12; ++c) ob[c] = (float)atom[c];
  const int base1 = B_ * KOUT_ * 12;                  // 98304: mask_sel
  out[base1 + idx]                  = read_mask(mask, g, mi32) ? 1.0f : 0.0f;
  out[base1 + B_ * KOUT_ + idx]     = (float)rule[g];     // rule_sel
  out[base1 + 2 * B_ * KOUT_ + idx] = score;              // top_scores
}

extern "C" void kernel_launch(void* const* d_in, const int* in_sizes, int n_in,
                              void* d_out, int out_size, void* d_ws, size_t ws_size,
                              hipStream_t stream) {
  const int*  body = (const int*)d_in[0];
  const void* mask = d_in[1];
  const int*  rule = (const int*)d_in[2];
  const float* ent = (const float*)d_in[3];
  const float* rel = (const float*)d_in[4];
  float* out = (float*)d_out;
  unsigned long long* keys = (unsigned long long*)d_ws;   // B*TG u64 = 1 MiB

  // 1) score: one wave per grounding; 4 waves per 256-thread block
  score_kernel<<<(B_ * TG_) / 4, 256, 0, stream>>>(body, mask, ent, rel, keys);
  // 2) per-row exact top-KOUT radix-select + LDS sort
  select_kernel<<<B_, 1024, 0, stream>>>(keys);
  // 3) gather + emit float32 outputs
  out_kernel<<<(B_ * KOUT_ + 255) / 256, 256, 0, stream>>>(keys, body, mask, rule, out);
}

// Round 5
// 149.379 us; speedup vs baseline: 10.0985x; 1.2670x over previous
//
#include <hip/hip_runtime.h>
#include <hip/hip_bf16.h>
#include <stdint.h>

// Problem constants (from reference)
constexpr int B_    = 4;
constexpr int TG_   = 32768;
constexpr int D_    = 128;
constexpr int KOUT_ = 2048;
constexpr int NB_   = 256;    // radix buckets (8 bits)
constexpr int NW_   = 16;     // waves per select block (1024 threads)
constexpr int CAP_  = 4096;   // candidate buffer (power of 2, >= KOUT + tie group)
#define BIGF 1e9f

// Monotonic float->uint map (ascending)
__device__ __forceinline__ uint32_t f2u_asc(float f) {
  uint32_t b = __float_as_uint(f);
  return (b & 0x80000000u) ? ~b : (b | 0x80000000u);
}
__device__ __forceinline__ float u2f_asc(uint32_t u) {
  uint32_t b = (u & 0x80000000u) ? (u & 0x7FFFFFFFu) : ~u;
  return __uint_as_float(b);
}

// mask dtype sniff: int32-bool array has first 16 words all in {0,1};
// a uint8-bool array (90% ones) cannot (P ~ 1e-48).
__device__ __forceinline__ bool mask_is_i32(const void* mask_raw) {
  const uint32_t* mw = (const uint32_t*)mask_raw;
  bool i32 = true;
  #pragma unroll
  for (int j = 0; j < 16; ++j) i32 &= (mw[j] <= 1u);
  return i32;
}
__device__ __forceinline__ int read_mask(const void* mask_raw, int idx, bool i32) {
  return i32 ? ((const int*)mask_raw)[idx]
             : (int)((const unsigned char*)mask_raw)[idx];
}

// One wave per grounding; 16 lanes per atom (4 atoms in parallel).
// Each lane loads 2 float4 per row (s,r,o) -> 6 independent dwordx4 loads.
// Padded atoms (sid==0) redirect rid/oid to row 0 (valid, hot) and get BIG.
__global__ __launch_bounds__(256) void score_kernel(
    const int* __restrict__ body, const void* __restrict__ mask,
    const float* __restrict__ ent, const float* __restrict__ rel,
    unsigned long long* __restrict__ keys) {
  int wid  = (blockIdx.x * 256 + threadIdx.x) >> 6;   // grounding id
  int lane = threadIdx.x & 63;
  if (wid >= B_ * TG_) return;
  int grp = lane >> 4;                                // atom index 0..3
  int sl  = lane & 15;                                // lane within atom group
  const int* atom = body + (long)wid * 12 + grp * 3;
  int sid = atom[0];
  bool padded = (sid == 0);
  int rid = padded ? 0 : atom[1];
  int oid = padded ? 0 : atom[2];
  const float4* sp = (const float4*)(ent + (long)sid * D_) + sl * 2;
  const float4* rp = (const float4*)(rel + (long)rid * D_) + sl * 2;
  const float4* op = (const float4*)(ent + (long)oid * D_) + sl * 2;
  float4 s0 = sp[0], s1 = sp[1];
  float4 r0 = rp[0], r1 = rp[1];
  float4 o0 = op[0], o1 = op[1];
  float p = s0.x*r0.x*o0.x + s0.y*r0.y*o0.y + s0.z*r0.z*o0.z + s0.w*r0.w*o0.w
          + s1.x*r1.x*o1.x + s1.y*r1.y*o1.y + s1.z*r1.z*o1.z + s1.w*r1.w*o1.w;
  // reduce the 16-lane group (xor stays within the aligned 16-block)
  p += __shfl_xor(p, 1);  p += __shfl_xor(p, 2);
  p += __shfl_xor(p, 4);  p += __shfl_xor(p, 8);
  p = padded ? BIGF : p;
  // min-conjunction across the 4 atom groups
  p = fminf(p, __shfl_xor(p, 16));
  p = fminf(p, __shfl_xor(p, 32));
  float score = read_mask(mask, wid, mask_is_i32(mask)) ? p : -BIGF;
  if (lane == 0) {
    uint32_t dk = ~f2u_asc(score);                    // ascending dk == descending score
    keys[wid] = ((unsigned long long)dk << 32) | (uint32_t)(wid & (TG_ - 1));
  }
}

// Per-row exact top-KOUT: early-exit radix-select over dk (high 32 bits),
// wave-private aggregated histograms, compact into LDS, bitonic sort CAP_,
// then write all four float32 outputs directly (fused epilogue).
__global__ __launch_bounds__(1024) void select_kernel(
    const unsigned long long* __restrict__ keys, const int* __restrict__ body,
    const void* __restrict__ mask, const int* __restrict__ rule,
    float* __restrict__ out) {
  const unsigned long long* a = keys + (long)blockIdx.x * TG_;
  __shared__ uint32_t hist[NW_][NB_];
  __shared__ uint32_t scan_[NB_];
  __shared__ unsigned long long cand[CAP_];
  __shared__ uint32_t s_cnt, s_prefix, s_below;
  __shared__ int s_k, s_done;
  int tid  = threadIdx.x;
  int wv   = tid >> 6;
  int lane = tid & 63;
  if (tid == 0) s_cnt = 0;

  uint32_t prefix = 0, below = 0;
  int k = KOUT_;                       // rank among prefix-matching keys
  int shift = 24;
  for (int pass = 0; pass < 4; ++pass) {
    shift = 24 - pass * 8;
    for (int i = tid; i < NW_ * NB_; i += 1024) ((uint32_t*)hist)[i] = 0;
    __syncthreads();
    uint32_t pmask = 0, pcmp = 0;
    if (pass) { pmask = 0xFFFFFFFFu << (shift + 8); pcmp = prefix << (shift + 8); }
    for (int i = tid; i < TG_; i += 1024) {
      uint32_t dk = (uint32_t)(a[i] >> 32);
      if ((dk & pmask) == pcmp) {
        int bin = (dk >> shift) & 0xFF;
        unsigned long long act = __ballot(1);
        int first = __builtin_amdgcn_readfirstlane(bin);
        if (__all(bin == first)) {     // clustered fast path: one atomic per wave
          if (lane == (int)__builtin_ctzll(act))
            atomicAdd(&hist[wv][first], (uint32_t)__popcll(act));
        } else {
          atomicAdd(&hist[wv][bin], 1u);  // wave-private copy: low contention
        }
      }
    }
    __syncthreads();
    if (tid < NB_) {
      uint32_t s = 0;
      #pragma unroll
      for (int w = 0; w < NW_; ++w) s += hist[w][tid];
      scan_[tid] = s;
    }
    __syncthreads();
    for (int off = 1; off < NB_; off <<= 1) {   // inclusive Hillis-Steele scan
      uint32_t v = 0;
      if (tid < NB_ && tid >= off) v = scan_[tid - off];
      __syncthreads();
      if (tid < NB_) scan_[tid] += v;
      __syncthreads();
    }
    if (tid < NB_) {
      uint32_t inc = scan_[tid];
      uint32_t abv = tid ? scan_[tid - 1] : 0u;
      if (inc >= (uint32_t)k && abv < (uint32_t)k) {   // unique digit
        s_prefix = (prefix << 8) | (uint32_t)tid;
        s_k      = k - (int)abv;
        s_below  = below + abv;
        s_done   = (below + inc <= (uint32_t)CAP_);    // below' + tie <= CAP?
      }
    }
    __syncthreads();
    prefix = s_prefix; k = s_k; below = s_below;
    int done = s_done;
    __syncthreads();
    if (done) break;                   // uniform (from shared)
  }

  // Compact: all keys whose (32-shift)-bit prefix <= threshold prefix.
  for (int i = tid; i < TG_; i += 1024) {
    unsigned long long key = a[i];
    if ((uint32_t)((key >> 32) >> shift) <= prefix) {
      uint32_t pos = atomicAdd(&s_cnt, 1u);
      if (pos < CAP_) cand[pos] = key;
    }
  }
  __syncthreads();
  uint32_t n = s_cnt < (uint32_t)CAP_ ? s_cnt : (uint32_t)CAP_;
  for (int i = (int)n + tid; i < CAP_; i += 1024) cand[i] = ~0ull;
  __syncthreads();
  // Bitonic sort CAP_ ascending in LDS (key order == jax top_k order).
  for (int kk = 2; kk <= CAP_; kk <<= 1) {
    for (int j = kk >> 1; j > 0; j >>= 1) {
      for (int i = tid; i < CAP_; i += 1024) {
        int l = i ^ j;
        if (l > i) {
          unsigned long long ai = cand[i], al = cand[l];
          bool up = ((i & kk) == 0);
          if ((ai > al) == up) { cand[i] = al; cand[l] = ai; }
        }
      }
      __syncthreads();
    }
  }
  // Fused epilogue: gather + emit all four outputs as float32.
  bool mi32 = mask_is_i32(mask);
  int b = blockIdx.x;
  for (int i = tid; i < KOUT_; i += 1024) {
    unsigned long long key = cand[i];
    int t = (int)(key & 0xFFFFFFFFu);
    float sc = u2f_asc(~(uint32_t)(key >> 32));
    int g = b * TG_ + t;
    int idx = b * KOUT_ + i;
    const int* at = body + (long)g * 12;
    float* ob = out + (long)idx * 12;               // body_sel [0, 98304)
    #pragma unroll
    for (int c = 0; c < 12; ++c) ob[c] = (float)at[c];
    const int base1 = B_ * KOUT_ * 12;              // 98304: mask_sel
    out[base1 + idx]                  = read_mask(mask, g, mi32) ? 1.0f : 0.0f;
    out[base1 + B_ * KOUT_ + idx]     = (float)rule[g];
    out[base1 + 2 * B_ * KOUT_ + idx] = sc;
  }
}

extern "C" void kernel_launch(void* const* d_in, const int* in_sizes, int n_in,
                              void* d_out, int out_size, void* d_ws, size_t ws_size,
                              hipStream_t stream) {
  const int*  body = (const int*)d_in[0];
  const void* mask = d_in[1];
  const int*  rule = (const int*)d_in[2];
  const float* ent = (const float*)d_in[3];
  const float* rel = (const float*)d_in[4];
  float* out = (float*)d_out;
  unsigned long long* keys = (unsigned long long*)d_ws;   // B*TG u64 = 1 MiB

  // 1) score: one wave per grounding; 16 lanes per atom
  score_kernel<<<(B_ * TG_) / 4, 256, 0, stream>>>(body, mask, ent, rel, keys);
  // 2) per-row exact top-KOUT radix-select + LDS sort + fused output
  select_kernel<<<B_, 1024, 0, stream>>>(keys, body, mask, rule, out);
}